// Round 8
// baseline (552.147 us; speedup 1.0000x reference)
//
#include <hip/hip_runtime.h>

// Bond harmonic energy with scatter-add onto first atom of each bond.
// R8: latency/MLP-bound regime (VALUBusy 1.8%, BW 36%) -> 4 bonds/thread so
// each wave keeps 8 independent float4 gathers in flight before waiting.

__global__ void pad_xyz_kernel(const float* __restrict__ xyz,
                               float4* __restrict__ xyz4, int n_atoms) {
    int i = blockIdx.x * blockDim.x + threadIdx.x;
    if (i < n_atoms) {
        const float* p = xyz + (size_t)i * 3;
        xyz4[i] = make_float4(p[0], p[1], p[2], 0.0f);
    }
}

// Four bonds per thread: maximize independent loads in flight.
__global__ void bond_energy4_kernel(const float4* __restrict__ xyz4,
                                    const int4* __restrict__ adj2,   // [E/2], 2 bonds each
                                    const float4* __restrict__ blen4, // [E/4]
                                    const float4* __restrict__ bpar4, // [E/4]
                                    float* __restrict__ out,
                                    int n_quads) {
    int i = blockIdx.x * blockDim.x + threadIdx.x;
    if (i >= n_quads) return;

    int4   ab01 = adj2[2 * i];
    int4   ab23 = adj2[2 * i + 1];
    float4 bl   = blen4[i];
    float4 bp   = bpar4[i];

    // 8 independent gathers — issue all before use.
    float4 p0a = xyz4[ab01.x];
    float4 p0b = xyz4[ab01.y];
    float4 p1a = xyz4[ab01.z];
    float4 p1b = xyz4[ab01.w];
    float4 p2a = xyz4[ab23.x];
    float4 p2b = xyz4[ab23.y];
    float4 p3a = xyz4[ab23.z];
    float4 p3b = xyz4[ab23.w];

    float dx0 = p0a.x - p0b.x, dy0 = p0a.y - p0b.y, dz0 = p0a.z - p0b.z;
    float dx1 = p1a.x - p1b.x, dy1 = p1a.y - p1b.y, dz1 = p1a.z - p1b.z;
    float dx2 = p2a.x - p2b.x, dy2 = p2a.y - p2b.y, dz2 = p2a.z - p2b.z;
    float dx3 = p3a.x - p3b.x, dy3 = p3a.y - p3b.y, dz3 = p3a.z - p3b.z;

    float e0 = sqrtf(dx0 * dx0 + dy0 * dy0 + dz0 * dz0);
    float e1 = sqrtf(dx1 * dx1 + dy1 * dy1 + dz1 * dz1);
    float e2 = sqrtf(dx2 * dx2 + dy2 * dy2 + dz2 * dz2);
    float e3 = sqrtf(dx3 * dx3 + dy3 * dy3 + dz3 * dz3);

    float d0 = e0 - bl.x, d1 = e1 - bl.y, d2 = e2 - bl.z, d3 = e3 - bl.w;
    float v0 = 0.5f * bp.x * d0 * d0;
    float v1 = 0.5f * bp.y * d1 * d1;
    float v2 = 0.5f * bp.z * d2 * d2;
    float v3 = 0.5f * bp.w * d3 * d3;

    atomicAdd(&out[ab01.x], v0);
    atomicAdd(&out[ab01.z], v1);
    atomicAdd(&out[ab23.x], v2);
    atomicAdd(&out[ab23.z], v3);
}

// Tail / fallback: 1 bond per thread, unpadded xyz.
__global__ void bond_energy_kernel(const float* __restrict__ xyz,
                                   const int2* __restrict__ adj,
                                   const float* __restrict__ blen,
                                   const float* __restrict__ bpar,
                                   float* __restrict__ out,
                                   int first, int n_bonds) {
    int i = first + blockIdx.x * blockDim.x + threadIdx.x;
    if (i >= n_bonds) return;
    int2 ab = adj[i];
    const float* p0 = xyz + (size_t)ab.x * 3;
    const float* p1 = xyz + (size_t)ab.y * 3;
    float dx = p0[0] - p1[0];
    float dy = p0[1] - p1[1];
    float dz = p0[2] - p1[2];
    float e = sqrtf(dx * dx + dy * dy + dz * dz);
    float d = e - blen[i];
    float v = 0.5f * bpar[i] * d * d;
    atomicAdd(&out[ab.x], v);
}

extern "C" void kernel_launch(void* const* d_in, const int* in_sizes, int n_in,
                              void* d_out, int out_size, void* d_ws, size_t ws_size,
                              hipStream_t stream) {
    const float* xyz  = (const float*)d_in[0];
    const int*   adj  = (const int*)d_in[1];
    const float* blen = (const float*)d_in[2];
    const float* bpar = (const float*)d_in[3];
    float* out = (float*)d_out;

    const int n_bonds = in_sizes[1] / 2;   // [E,2] flat
    const int n_atoms = in_sizes[0] / 3;   // [N,3] flat

    // out is poisoned with 0xAA before every timed launch — zero it.
    (void)hipMemsetAsync(d_out, 0, (size_t)out_size * sizeof(float), stream);

    const int block = 256;
    const size_t pad_bytes = (size_t)n_atoms * 4 * sizeof(float);

    if (ws_size >= pad_bytes) {
        float4* xyz4 = (float4*)d_ws;
        pad_xyz_kernel<<<(n_atoms + block - 1) / block, block, 0, stream>>>(
            xyz, xyz4, n_atoms);

        const int n_quads = n_bonds / 4;
        if (n_quads > 0) {
            bond_energy4_kernel<<<(n_quads + block - 1) / block, block, 0, stream>>>(
                xyz4, (const int4*)adj, (const float4*)blen, (const float4*)bpar,
                out, n_quads);
        }
        const int done = n_quads * 4;
        const int tail = n_bonds - done;
        if (tail > 0) {
            bond_energy_kernel<<<(tail + block - 1) / block, block, 0, stream>>>(
                xyz, (const int2*)adj, blen, bpar, out, done, n_bonds);
        }
    } else {
        bond_energy_kernel<<<(n_bonds + block - 1) / block, block, 0, stream>>>(
            xyz, (const int2*)adj, blen, bpar, out, 0, n_bonds);
    }
}